// Round 1
// baseline (133.978 us; speedup 1.0000x reference)
//
#include <hip/hip_runtime.h>

#define NB_B 2
#define NB_E 1024
#define NB_DM 512
#define NB_H 8
#define NEGV -1e9f

typedef __attribute__((ext_vector_type(8))) __bf16 bf16x8;
typedef __attribute__((ext_vector_type(8))) unsigned short u16x8;
typedef __attribute__((ext_vector_type(4))) float f32x4;

static __device__ __forceinline__ float bf2f(unsigned short u){
  union { unsigned int i; float f; } v; v.i = ((unsigned int)u) << 16; return v.f;
}
static __device__ __forceinline__ unsigned short f2bf(float f){
  union { float f; unsigned int i; } v; v.f = f;
  unsigned int r = v.i + 0x7FFFu + ((v.i >> 16) & 1u);
  return (unsigned short)(r >> 16);
}
static __device__ __forceinline__ f32x4 mfma16(bf16x8 a, bf16x8 b, f32x4 c){
  return __builtin_amdgcn_mfma_f32_16x16x32_bf16(a, b, c, 0, 0, 0);
}

// ---- transpose x [B,DM,E] (f32) -> s_bf [B,E,DM] (bf16) ----
__global__ void k_transpose_x(const float* __restrict__ x, unsigned short* __restrict__ s_bf){
  __shared__ float tile[32][33];
  const int b = blockIdx.z;
  const int d0 = blockIdx.y * 32;
  const int e0 = blockIdx.x * 32;
  const int tx = threadIdx.x, ty = threadIdx.y;
  #pragma unroll
  for (int r = 0; r < 4; ++r){
    const int d = d0 + ty + r*8;
    tile[ty + r*8][tx] = x[((size_t)b*NB_DM + d)*NB_E + e0 + tx];
  }
  __syncthreads();
  #pragma unroll
  for (int r = 0; r < 4; ++r){
    const int e = e0 + ty + r*8;
    s_bf[((size_t)b*NB_E + e)*NB_DM + d0 + tx] = f2bf(tile[tx][ty + r*8]);
  }
}

// ---- transpose 4 weights [512,512] f32 -> wT bf16 [which][n][k] ----
__global__ void k_transpose_w(const float* __restrict__ w0, const float* __restrict__ w1,
                              const float* __restrict__ w2, const float* __restrict__ w3,
                              unsigned short* __restrict__ wT){
  __shared__ float tile[32][33];
  const int which = blockIdx.z;
  const float* w = which==0 ? w0 : which==1 ? w1 : which==2 ? w2 : w3;
  unsigned short* dst = wT + (size_t)which*512*512;
  const int k0 = blockIdx.y*32, n0 = blockIdx.x*32;
  const int tx = threadIdx.x, ty = threadIdx.y;
  #pragma unroll
  for (int r = 0; r < 4; ++r)
    tile[ty + r*8][tx] = w[(size_t)(k0 + ty + r*8)*512 + n0 + tx];
  __syncthreads();
  #pragma unroll
  for (int r = 0; r < 4; ++r)
    dst[(size_t)(n0 + ty + r*8)*512 + k0 + tx] = f2bf(tile[tx][ty + r*8]);
}

// ---- layernorm rows of s_bf -> qn_bf ----
__global__ __launch_bounds__(64) void k_ln(const unsigned short* __restrict__ s_bf,
    unsigned short* __restrict__ qn_bf, const float* __restrict__ gg, const float* __restrict__ bb){
  const int row = blockIdx.x, l = threadIdx.x;
  const unsigned short* sp = s_bf + (size_t)row*512 + l*8;
  u16x8 v = *(const u16x8*)sp;
  float f[8]; float sum = 0.f, sq = 0.f;
  #pragma unroll
  for (int i = 0; i < 8; ++i){ f[i] = bf2f(v[i]); sum += f[i]; sq += f[i]*f[i]; }
  #pragma unroll
  for (int off = 32; off >= 1; off >>= 1){
    sum += __shfl_xor(sum, off);
    sq  += __shfl_xor(sq, off);
  }
  const float mu  = sum * (1.f/512.f);
  const float var = sq * (1.f/512.f) - mu*mu;
  const float rstd = rsqrtf(var + 1e-6f);
  const float4 g0 = *(const float4*)(gg + l*8);
  const float4 g1 = *(const float4*)(gg + l*8 + 4);
  const float4 b0 = *(const float4*)(bb + l*8);
  const float4 b1 = *(const float4*)(bb + l*8 + 4);
  const float gv[8] = {g0.x,g0.y,g0.z,g0.w,g1.x,g1.y,g1.z,g1.w};
  const float bv[8] = {b0.x,b0.y,b0.z,b0.w,b1.x,b1.y,b1.z,b1.w};
  u16x8 o;
  #pragma unroll
  for (int i = 0; i < 8; ++i) o[i] = f2bf((f[i]-mu)*rstd*gv[i] + bv[i]);
  *(u16x8*)(qn_bf + (size_t)row*512 + l*8) = o;
}

// ---- classify dist -> uint8 (0..5 = rpr class, 6 = masked) ----
__global__ void k_dist8(const int* __restrict__ dist, unsigned char* __restrict__ d8){
  const int idx = blockIdx.x*256 + threadIdx.x;
  const int4 d = ((const int4*)dist)[idx];
  uchar4 o;
  o.x = (unsigned char)(d.x <= 5 ? d.x : 6);
  o.y = (unsigned char)(d.y <= 5 ? d.y : 6);
  o.z = (unsigned char)(d.z <= 5 ? d.z : 6);
  o.w = (unsigned char)(d.w <= 5 ? d.w : 6);
  ((uchar4*)d8)[idx] = o;
}

// ---- per-column mask counts ----
__global__ void k_cnt(const unsigned char* __restrict__ d8, int* __restrict__ cnt){
  const int b = blockIdx.y;
  const int i0 = blockIdx.x*32;
  const int tid = threadIdx.x;
  #pragma unroll
  for (int jj = 0; jj < 4; ++jj){
    const int j = tid + jj*256;
    int c = 0;
    #pragma unroll 8
    for (int i = 0; i < 32; ++i)
      c += (d8[((size_t)b*NB_E + i0 + i)*NB_E + j] < 6) ? 1 : 0;
    atomicAdd(&cnt[b*NB_E + j], c);
  }
}

// ---- qr table: qr[g][c] = dot(qs_row[g], base_rpr[c]) ----
__global__ __launch_bounds__(256) void k_qr(const unsigned short* __restrict__ Q,
    const float* __restrict__ base_rpr, float* __restrict__ qr){
  __shared__ float rl[384];
  const int tid = threadIdx.x;
  for (int t = tid; t < 384; t += 256) rl[t] = base_rpr[t];
  __syncthreads();
  const int g = blockIdx.x*256 + tid;
  const unsigned short* qp = Q + (size_t)g*64;
  float qv[64];
  #pragma unroll
  for (int i = 0; i < 8; ++i){
    u16x8 v = *(const u16x8*)(qp + i*8);
    #pragma unroll
    for (int j = 0; j < 8; ++j) qv[i*8+j] = bf2f(v[j]);
  }
  #pragma unroll
  for (int c = 0; c < 6; ++c){
    float sacc = 0.f;
    #pragma unroll
    for (int d = 0; d < 64; ++d) sacc += qv[d]*rl[c*64 + d];
    qr[(size_t)g*8 + c] = sacc;
  }
}

// ---- generic MFMA GEMM: C[M=2048, N=512] = A[M,512] * BT[N,512]^T ----
// MODE 0: write Q bf16 [B,H,E,64], scaled 1/8
// MODE 1: write K bf16 [B,H,E,64]
// MODE 2: write VT bf16 [B,H,64,E]
// MODE 3: write x_out f32 [B,DM,E] (+ residual from x)
template<int MODE>
__global__ __launch_bounds__(256) void k_gemm(
    const unsigned short* __restrict__ A, const unsigned short* __restrict__ BT,
    unsigned short* __restrict__ dst_bf, float* __restrict__ dst_f,
    const float* __restrict__ resid)
{
  const int tid = threadIdx.x;
  const int l = tid & 63, wv = tid >> 6;
  const int ll = l & 15, lg = l >> 4;
  const int m0 = blockIdx.x*64 + wv*16;
  const int n0 = blockIdx.y*64;
  const unsigned short* arow = A + (size_t)(m0 + ll)*512 + lg*8;
  f32x4 acc[4];
  #pragma unroll
  for (int nt = 0; nt < 4; ++nt) acc[nt] = (f32x4){0.f,0.f,0.f,0.f};
  #pragma unroll
  for (int ks = 0; ks < 16; ++ks){
    bf16x8 a = *(const bf16x8*)(arow + ks*32);
    #pragma unroll
    for (int nt = 0; nt < 4; ++nt){
      bf16x8 bv = *(const bf16x8*)(BT + (size_t)(n0 + nt*16 + ll)*512 + ks*32 + lg*8);
      acc[nt] = mfma16(a, bv, acc[nt]);
    }
  }
  const int rbase = m0 + lg*4;          // 4 consecutive rows, same b
  const int bidx = rbase >> 10;
  const int e = rbase & 1023;
  #pragma unroll
  for (int nt = 0; nt < 4; ++nt){
    const int n = n0 + nt*16 + ll;
    if (MODE == 0 || MODE == 1){
      const int h = n >> 6, dk = n & 63;
      unsigned short* dp = dst_bf + (((size_t)bidx*NB_H + h)*NB_E + e)*64 + dk;
      #pragma unroll
      for (int r = 0; r < 4; ++r)
        dp[(size_t)r*64] = f2bf(MODE == 0 ? acc[nt][r]*0.125f : acc[nt][r]);
    } else if (MODE == 2){
      const int h = n >> 6, dv = n & 63;
      ushort4 ov;
      ov.x = f2bf(acc[nt][0]); ov.y = f2bf(acc[nt][1]);
      ov.z = f2bf(acc[nt][2]); ov.w = f2bf(acc[nt][3]);
      *(ushort4*)(dst_bf + (((size_t)bidx*NB_H + h)*64 + dv)*NB_E + e) = ov;
    } else {
      const float* xr = resid + ((size_t)bidx*NB_DM + n)*NB_E + e;
      const float4 rv = *(const float4*)xr;
      const float4 ov = make_float4(acc[nt][0]+rv.x, acc[nt][1]+rv.y,
                                    acc[nt][2]+rv.z, acc[nt][3]+rv.w);
      *(float4*)(dst_f + ((size_t)bidx*NB_DM + n)*NB_E + e) = ov;
    }
  }
}

// ---- fused attention: block = (b,h, 32-row i-tile); 4 waves x 256-col chunks ----
__global__ __launch_bounds__(256, 2) void k_attn(
    const unsigned short* __restrict__ Q, const unsigned short* __restrict__ K,
    const unsigned short* __restrict__ VT, const float* __restrict__ qr,
    const unsigned char* __restrict__ d8, float* __restrict__ attn_out,
    unsigned short* __restrict__ outb, float* __restrict__ ape_acc)
{
  __shared__ __align__(16) unsigned char smem[65536];      // P tile bf16 [32][1024], swizzled
  unsigned short* plds = (unsigned short*)smem;
  float* qr_l = (float*)smem;                 // bytes [0,768): qr table (dead before P writes)
  float* redm = (float*)(smem + 768);         // [4*32]
  float* reds = (float*)(smem + 1280);        // [4*32]

  const int tid = threadIdx.x;
  const int l = tid & 63, w = tid >> 6;
  const int lg = l >> 4, ll = l & 15;
  const int bh = blockIdx.y;                  // b*H + h
  const int b = bh >> 3;
  const int ib = blockIdx.x << 5;

  for (int t = tid; t < 32*6; t += 256)
    qr_l[t] = qr[((size_t)bh*NB_E + ib + (t/6))*8 + (t % 6)];

  const unsigned short* Qb = Q + ((size_t)bh*NB_E + ib)*64;
  bf16x8 qf[2][2];
  #pragma unroll
  for (int it = 0; it < 2; ++it)
    #pragma unroll
    for (int hf = 0; hf < 2; ++hf)
      qf[it][hf] = *(const bf16x8*)(Qb + (size_t)(it*16 + ll)*64 + hf*32 + lg*8);
  __syncthreads();

  // S = (Q/8) K^T
  f32x4 s[2][16];
  const unsigned short* Kb = K + (size_t)bh*NB_E*64;
  #pragma unroll
  for (int jt = 0; jt < 16; ++jt){
    const int jrow = (w*16 + jt)*16 + ll;
    bf16x8 k0 = *(const bf16x8*)(Kb + (size_t)jrow*64 + lg*8);
    bf16x8 k1 = *(const bf16x8*)(Kb + (size_t)jrow*64 + 32 + lg*8);
    #pragma unroll
    for (int it = 0; it < 2; ++it){
      f32x4 acc = {0.f,0.f,0.f,0.f};
      acc = mfma16(qf[it][0], k0, acc);
      acc = mfma16(qf[it][1], k1, acc);
      s[it][jt] = acc;
    }
  }

  // + rpr bias, mask
  const unsigned char* d8r = d8 + ((size_t)b*NB_E + ib)*NB_E;
  #pragma unroll
  for (int it = 0; it < 2; ++it)
  #pragma unroll
  for (int jt = 0; jt < 16; ++jt){
    const int j = (w*16 + jt)*16 + ll;
    #pragma unroll
    for (int r = 0; r < 4; ++r){
      const int il = it*16 + lg*4 + r;
      const unsigned char c = d8r[(size_t)il*NB_E + j];
      s[it][jt][r] = (c < 6) ? (s[it][jt][r] + qr_l[il*6 + c]) : NEGV;
    }
  }

  // row max across waves
  float mx[2][4];
  #pragma unroll
  for (int it = 0; it < 2; ++it)
    #pragma unroll
    for (int r = 0; r < 4; ++r){
      float m = -3.0e38f;
      #pragma unroll
      for (int jt = 0; jt < 16; ++jt) m = fmaxf(m, s[it][jt][r]);
      m = fmaxf(m, __shfl_xor(m, 1));
      m = fmaxf(m, __shfl_xor(m, 2));
      m = fmaxf(m, __shfl_xor(m, 4));
      m = fmaxf(m, __shfl_xor(m, 8));
      if (ll == 0) redm[w*32 + it*16 + lg*4 + r] = m;
    }
  __syncthreads();
  #pragma unroll
  for (int it = 0; it < 2; ++it)
    #pragma unroll
    for (int r = 0; r < 4; ++r){
      const int il = it*16 + lg*4 + r;
      mx[it][r] = fmaxf(fmaxf(redm[il], redm[32+il]), fmaxf(redm[64+il], redm[96+il]));
    }

  // exp + row sum across waves
  float rinv[2][4];
  #pragma unroll
  for (int it = 0; it < 2; ++it)
    #pragma unroll
    for (int r = 0; r < 4; ++r){
      float sum = 0.f;
      #pragma unroll
      for (int jt = 0; jt < 16; ++jt){
        const float p = exp2f((s[it][jt][r] - mx[it][r]) * 1.4426950408889634f);
        s[it][jt][r] = p;
        sum += p;
      }
      sum += __shfl_xor(sum, 1);
      sum += __shfl_xor(sum, 2);
      sum += __shfl_xor(sum, 4);
      sum += __shfl_xor(sum, 8);
      if (ll == 0) reds[w*32 + it*16 + lg*4 + r] = sum;
    }
  __syncthreads();
  #pragma unroll
  for (int it = 0; it < 2; ++it)
    #pragma unroll
    for (int r = 0; r < 4; ++r){
      const int il = it*16 + lg*4 + r;
      rinv[it][r] = 1.0f / (reds[il] + reds[32+il] + reds[64+il] + reds[96+il]);
    }
  __syncthreads();   // all reds/qr_l reads done before P writes alias them

  // normalize: write attn (f32 global), P (bf16 LDS, XOR-swizzled), column sums
  float* arow = attn_out + ((size_t)bh*NB_E + ib)*NB_E;
  #pragma unroll
  for (int jt = 0; jt < 16; ++jt){
    const int j = (w*16 + jt)*16 + ll;
    float csum = 0.f;
    #pragma unroll
    for (int it = 0; it < 2; ++it)
      #pragma unroll
      for (int r = 0; r < 4; ++r){
        const int il = it*16 + lg*4 + r;
        const float pn = s[it][jt][r] * rinv[it][r];
        arow[(size_t)il*NB_E + j] = pn;
        const int byo = ((il*1024 + j)*2) ^ ((il & 7) << 4);
        plds[byo >> 1] = f2bf(pn);
        csum += pn;
      }
    csum += __shfl_xor(csum, 16);
    csum += __shfl_xor(csum, 32);
    if (l < 16) atomicAdd(&ape_acc[b*NB_E + j], csum);
  }
  __syncthreads();

  // PV: wave w -> dv chunk [w*16, w*16+16)
  const unsigned short* Vb = VT + ((size_t)bh*64 + w*16 + ll)*NB_E;
  f32x4 o0 = {0.f,0.f,0.f,0.f}, o1 = {0.f,0.f,0.f,0.f};
  #pragma unroll
  for (int kk = 0; kk < 32; ++kk){
    bf16x8 vf = *(const bf16x8*)(Vb + kk*32 + lg*8);
    {
      const int i0 = ll;
      const int byo = ((i0*1024 + kk*32 + lg*8)*2) ^ ((i0 & 7) << 4);
      bf16x8 p0 = *(const bf16x8*)(smem + byo);
      o0 = mfma16(p0, vf, o0);
    }
    {
      const int i1 = 16 + ll;
      const int byo = ((i1*1024 + kk*32 + lg*8)*2) ^ ((i1 & 7) << 4);
      bf16x8 p1 = *(const bf16x8*)(smem + byo);
      o1 = mfma16(p1, vf, o1);
    }
  }
  const int coln = (bh & 7)*64 + w*16 + ll;
  #pragma unroll
  for (int r = 0; r < 4; ++r){
    const int e0 = ib + lg*4 + r;
    outb[((size_t)b*NB_E + e0)*512 + coln] = f2bf(o0[r]);
    const int e1 = ib + 16 + lg*4 + r;
    outb[((size_t)b*NB_E + e1)*512 + coln] = f2bf(o1[r]);
  }
}

// ---- attn_per_edge finalize ----
__global__ void k_ape(const float* __restrict__ acc, const int* __restrict__ cnt,
                      float* __restrict__ out){
  const int t = blockIdx.x*256 + threadIdx.x;
  if (t < NB_B*NB_E){
    const int c = cnt[t];
    out[t] = c > 0 ? acc[t] / (float)c : 0.f;
  }
}

extern "C" void kernel_launch(void* const* d_in, const int* in_sizes, int n_in,
                              void* d_out, int out_size, void* d_ws, size_t ws_size,
                              hipStream_t stream)
{
  const float* x        = (const float*)d_in[0];
  const int*   dist     = (const int*)d_in[1];
  const float* base_rpr = (const float*)d_in[2];
  const float* w_q      = (const float*)d_in[3];
  const float* w_k      = (const float*)d_in[4];
  const float* w_v      = (const float*)d_in[5];
  const float* w_fc     = (const float*)d_in[6];
  const float* ln_g     = (const float*)d_in[7];
  const float* ln_b     = (const float*)d_in[8];

  float* x_out    = (float*)d_out;
  float* attn_out = x_out + (size_t)NB_B*NB_DM*NB_E;
  float* ape_out  = attn_out + (size_t)NB_B*NB_H*NB_E*NB_E;

  unsigned char* ws = (unsigned char*)d_ws;
  unsigned short* s_bf   = (unsigned short*)(ws);
  unsigned short* qn_bf  = (unsigned short*)(ws + 2097152);
  unsigned short* wT     = (unsigned short*)(ws + 4194304);   // 4 x 512x512 bf16
  unsigned short* Qb     = (unsigned short*)(ws + 6291456);
  unsigned short* Kb     = (unsigned short*)(ws + 8388608);
  unsigned short* VTb    = (unsigned short*)(ws + 10485760);
  unsigned short* outb   = (unsigned short*)(ws + 12582912);
  float*          qr     = (float*)(ws + 14680064);
  unsigned char*  d8     = ws + 15204352;
  int*            cnt    = (int*)(ws + 17301504);
  float*          apeacc = (float*)(ws + 17309696);

  hipMemsetAsync(cnt, 0, NB_B*NB_E*sizeof(int), stream);
  hipMemsetAsync(apeacc, 0, NB_B*NB_E*sizeof(float), stream);

  k_transpose_w<<<dim3(16,16,4), dim3(32,8), 0, stream>>>(w_q, w_k, w_v, w_fc, wT);
  k_transpose_x<<<dim3(32,16,2), dim3(32,8), 0, stream>>>(x, s_bf);
  k_ln<<<dim3(2048), dim3(64), 0, stream>>>(s_bf, qn_bf, ln_g, ln_b);
  k_dist8<<<dim3(2048), dim3(256), 0, stream>>>(dist, d8);
  k_cnt<<<dim3(32,2), dim3(256), 0, stream>>>(d8, cnt);

  k_gemm<0><<<dim3(32,8), dim3(256), 0, stream>>>(qn_bf, wT,          Qb,  nullptr, nullptr);
  k_gemm<1><<<dim3(32,8), dim3(256), 0, stream>>>(s_bf,  wT + 262144, Kb,  nullptr, nullptr);
  k_gemm<2><<<dim3(32,8), dim3(256), 0, stream>>>(s_bf,  wT + 524288, VTb, nullptr, nullptr);
  k_qr<<<dim3(64), dim3(256), 0, stream>>>(Qb, base_rpr, qr);

  k_attn<<<dim3(32,16), dim3(256), 0, stream>>>(Qb, Kb, VTb, qr, d8, attn_out, outb, apeacc);

  k_gemm<3><<<dim3(32,8), dim3(256), 0, stream>>>(outb, wT + 786432, nullptr, x_out, x);
  k_ape<<<dim3(8), dim3(256), 0, stream>>>(apeacc, cnt, ape_out);
}

// Round 2
// 122.398 us; speedup vs baseline: 1.0946x; 1.0946x over previous
//
#include <hip/hip_runtime.h>

#define NB_B 2
#define NB_E 1024
#define NB_DM 512
#define NB_H 8
#define NEGV -1e9f

typedef __attribute__((ext_vector_type(8))) __bf16 bf16x8;
typedef __attribute__((ext_vector_type(8))) unsigned short u16x8;
typedef __attribute__((ext_vector_type(4))) float f32x4;

static __device__ __forceinline__ float bf2f(unsigned short u){
  union { unsigned int i; float f; } v; v.i = ((unsigned int)u) << 16; return v.f;
}
static __device__ __forceinline__ unsigned short f2bf(float f){
  union { float f; unsigned int i; } v; v.f = f;
  unsigned int r = v.i + 0x7FFFu + ((v.i >> 16) & 1u);
  return (unsigned short)(r >> 16);
}
static __device__ __forceinline__ f32x4 mfma16(bf16x8 a, bf16x8 b, f32x4 c){
  return __builtin_amdgcn_mfma_f32_16x16x32_bf16(a, b, c, 0, 0, 0);
}
static __device__ __forceinline__ float fast_exp2(float x){
#if __has_builtin(__builtin_amdgcn_exp2f)
  return __builtin_amdgcn_exp2f(x);
#else
  return exp2f(x);
#endif
}

// ---- transpose x [B,DM,E] (f32) -> s_bf [B,E,DM] (bf16) ----
__global__ void k_transpose_x(const float* __restrict__ x, unsigned short* __restrict__ s_bf){
  __shared__ float tile[32][33];
  const int b = blockIdx.z;
  const int d0 = blockIdx.y * 32;
  const int e0 = blockIdx.x * 32;
  const int tx = threadIdx.x, ty = threadIdx.y;
  #pragma unroll
  for (int r = 0; r < 4; ++r){
    const int d = d0 + ty + r*8;
    tile[ty + r*8][tx] = x[((size_t)b*NB_DM + d)*NB_E + e0 + tx];
  }
  __syncthreads();
  #pragma unroll
  for (int r = 0; r < 4; ++r){
    const int e = e0 + ty + r*8;
    s_bf[((size_t)b*NB_E + e)*NB_DM + d0 + tx] = f2bf(tile[tx][ty + r*8]);
  }
}

// ---- transpose 4 weights [512,512] f32 -> wT bf16 [which][n][k] ----
__global__ void k_transpose_w(const float* __restrict__ w0, const float* __restrict__ w1,
                              const float* __restrict__ w2, const float* __restrict__ w3,
                              unsigned short* __restrict__ wT){
  __shared__ float tile[32][33];
  const int which = blockIdx.z;
  const float* w = which==0 ? w0 : which==1 ? w1 : which==2 ? w2 : w3;
  unsigned short* dst = wT + (size_t)which*512*512;
  const int k0 = blockIdx.y*32, n0 = blockIdx.x*32;
  const int tx = threadIdx.x, ty = threadIdx.y;
  #pragma unroll
  for (int r = 0; r < 4; ++r)
    tile[ty + r*8][tx] = w[(size_t)(k0 + ty + r*8)*512 + n0 + tx];
  __syncthreads();
  #pragma unroll
  for (int r = 0; r < 4; ++r)
    dst[(size_t)(n0 + ty + r*8)*512 + k0 + tx] = f2bf(tile[tx][ty + r*8]);
}

// ---- layernorm rows of s_bf -> qn_bf (4 rows per 256-thread block) ----
__global__ __launch_bounds__(256) void k_ln(const unsigned short* __restrict__ s_bf,
    unsigned short* __restrict__ qn_bf, const float* __restrict__ gg, const float* __restrict__ bb){
  const int row = blockIdx.x*4 + (threadIdx.x >> 6);
  const int l = threadIdx.x & 63;
  const unsigned short* sp = s_bf + (size_t)row*512 + l*8;
  u16x8 v = *(const u16x8*)sp;
  float f[8]; float sum = 0.f, sq = 0.f;
  #pragma unroll
  for (int i = 0; i < 8; ++i){ f[i] = bf2f(v[i]); sum += f[i]; sq += f[i]*f[i]; }
  #pragma unroll
  for (int off = 32; off >= 1; off >>= 1){
    sum += __shfl_xor(sum, off);
    sq  += __shfl_xor(sq, off);
  }
  const float mu  = sum * (1.f/512.f);
  const float var = sq * (1.f/512.f) - mu*mu;
  const float rstd = rsqrtf(var + 1e-6f);
  const float4 g0 = *(const float4*)(gg + l*8);
  const float4 g1 = *(const float4*)(gg + l*8 + 4);
  const float4 b0 = *(const float4*)(bb + l*8);
  const float4 b1 = *(const float4*)(bb + l*8 + 4);
  const float gv[8] = {g0.x,g0.y,g0.z,g0.w,g1.x,g1.y,g1.z,g1.w};
  const float bv[8] = {b0.x,b0.y,b0.z,b0.w,b1.x,b1.y,b1.z,b1.w};
  u16x8 o;
  #pragma unroll
  for (int i = 0; i < 8; ++i) o[i] = f2bf((f[i]-mu)*rstd*gv[i] + bv[i]);
  *(u16x8*)(qn_bf + (size_t)row*512 + l*8) = o;
}

// ---- classify dist -> uint8 (0..5 = rpr class, 6 = masked) + column counts ----
__global__ __launch_bounds__(256) void k_dist(const int* __restrict__ dist,
    unsigned char* __restrict__ d8, int* __restrict__ cnt){
  const int b = blockIdx.y;
  const int i0 = blockIdx.x * 16;
  const int t = threadIdx.x;
  int c0 = 0, c1 = 0, c2 = 0, c3 = 0;
  #pragma unroll 4
  for (int r = 0; r < 16; ++r){
    const int row = i0 + r;
    const int4 d = ((const int4*)(dist + ((size_t)b*NB_E + row)*NB_E))[t];
    uchar4 o;
    o.x = (unsigned char)(d.x <= 5 ? d.x : 6);
    o.y = (unsigned char)(d.y <= 5 ? d.y : 6);
    o.z = (unsigned char)(d.z <= 5 ? d.z : 6);
    o.w = (unsigned char)(d.w <= 5 ? d.w : 6);
    ((uchar4*)(d8 + ((size_t)b*NB_E + row)*NB_E))[t] = o;
    c0 += (d.x <= 5); c1 += (d.y <= 5); c2 += (d.z <= 5); c3 += (d.w <= 5);
  }
  int* cb = cnt + b*NB_E + t*4;
  atomicAdd(cb + 0, c0);
  atomicAdd(cb + 1, c1);
  atomicAdd(cb + 2, c2);
  atomicAdd(cb + 3, c3);
}

// ---- fused QKV GEMM: z=0 -> Q (scaled 1/8, + qr table), z=1 -> K, z=2 -> V^T ----
__global__ __launch_bounds__(256) void k_gemm_qkv(
    const unsigned short* __restrict__ qn, const unsigned short* __restrict__ s,
    const unsigned short* __restrict__ wT, const float* __restrict__ base_rpr,
    unsigned short* __restrict__ Qb, unsigned short* __restrict__ Kb,
    unsigned short* __restrict__ VTb, float* __restrict__ qr)
{
  const int z = blockIdx.z;
  const unsigned short* A  = (z == 0) ? qn : s;
  const unsigned short* BT = wT + (size_t)z*262144;
  const int tid = threadIdx.x;
  const int l = tid & 63, wv = tid >> 6;
  const int ll = l & 15, lg = l >> 4;
  const int m0 = blockIdx.x*64 + wv*16;
  const int n0 = blockIdx.y*64;
  const unsigned short* arow = A + (size_t)(m0 + ll)*512 + lg*8;
  f32x4 acc[4];
  #pragma unroll
  for (int nt = 0; nt < 4; ++nt) acc[nt] = (f32x4){0.f,0.f,0.f,0.f};
  #pragma unroll
  for (int ks = 0; ks < 16; ++ks){
    bf16x8 a = *(const bf16x8*)(arow + ks*32);
    #pragma unroll
    for (int nt = 0; nt < 4; ++nt){
      bf16x8 bv = *(const bf16x8*)(BT + (size_t)(n0 + nt*16 + ll)*512 + ks*32 + lg*8);
      acc[nt] = mfma16(a, bv, acc[nt]);
    }
  }
  const int rbase = m0 + lg*4;
  const int bidx = rbase >> 10;
  const int e = rbase & 1023;
  const int h = n0 >> 6;                       // one head per block column
  if (z == 0){
    // scale, write Q, and compute qr[g][c] = sum_d Qs[g][d]*rpr[c][d]
    float rprv[6][4];
    #pragma unroll
    for (int c = 0; c < 6; ++c)
      #pragma unroll
      for (int nt = 0; nt < 4; ++nt)
        rprv[c][nt] = base_rpr[c*64 + nt*16 + ll];
    #pragma unroll
    for (int nt = 0; nt < 4; ++nt){
      const int dk = nt*16 + ll;
      unsigned short* dp = Qb + (((size_t)bidx*NB_H + h)*NB_E + e)*64 + dk;
      #pragma unroll
      for (int r = 0; r < 4; ++r)
        dp[(size_t)r*64] = f2bf(acc[nt][r]*0.125f);
    }
    #pragma unroll
    for (int r = 0; r < 4; ++r){
      #pragma unroll
      for (int c = 0; c < 6; ++c){
        float tv = 0.f;
        #pragma unroll
        for (int nt = 0; nt < 4; ++nt) tv += acc[nt][r]*0.125f*rprv[c][nt];
        tv += __shfl_xor(tv, 1);
        tv += __shfl_xor(tv, 2);
        tv += __shfl_xor(tv, 4);
        tv += __shfl_xor(tv, 8);
        if (ll == 0)
          qr[(((size_t)(bidx*NB_H + h)*NB_E) + e + r)*8 + c] = tv;
      }
    }
  } else if (z == 1){
    #pragma unroll
    for (int nt = 0; nt < 4; ++nt){
      const int dk = nt*16 + ll;
      unsigned short* dp = Kb + (((size_t)bidx*NB_H + h)*NB_E + e)*64 + dk;
      #pragma unroll
      for (int r = 0; r < 4; ++r)
        dp[(size_t)r*64] = f2bf(acc[nt][r]);
    }
  } else {
    #pragma unroll
    for (int nt = 0; nt < 4; ++nt){
      const int dv = nt*16 + ll;
      ushort4 ov;
      ov.x = f2bf(acc[nt][0]); ov.y = f2bf(acc[nt][1]);
      ov.z = f2bf(acc[nt][2]); ov.w = f2bf(acc[nt][3]);
      *(ushort4*)(VTb + (((size_t)bidx*NB_H + h)*64 + dv)*NB_E + e) = ov;
    }
  }
}

// ---- FC GEMM: x_out f32 [B,DM,E] = outb @ w_fc^T + residual ----
__global__ __launch_bounds__(256) void k_fc(
    const unsigned short* __restrict__ A, const unsigned short* __restrict__ BT,
    float* __restrict__ dst_f, const float* __restrict__ resid)
{
  const int tid = threadIdx.x;
  const int l = tid & 63, wv = tid >> 6;
  const int ll = l & 15, lg = l >> 4;
  const int m0 = blockIdx.x*64 + wv*16;
  const int n0 = blockIdx.y*64;
  const unsigned short* arow = A + (size_t)(m0 + ll)*512 + lg*8;
  f32x4 acc[4];
  #pragma unroll
  for (int nt = 0; nt < 4; ++nt) acc[nt] = (f32x4){0.f,0.f,0.f,0.f};
  #pragma unroll
  for (int ks = 0; ks < 16; ++ks){
    bf16x8 a = *(const bf16x8*)(arow + ks*32);
    #pragma unroll
    for (int nt = 0; nt < 4; ++nt){
      bf16x8 bv = *(const bf16x8*)(BT + (size_t)(n0 + nt*16 + ll)*512 + ks*32 + lg*8);
      acc[nt] = mfma16(a, bv, acc[nt]);
    }
  }
  const int rbase = m0 + lg*4;
  const int bidx = rbase >> 10;
  const int e = rbase & 1023;
  #pragma unroll
  for (int nt = 0; nt < 4; ++nt){
    const int n = n0 + nt*16 + ll;
    const float* xr = resid + ((size_t)bidx*NB_DM + n)*NB_E + e;
    const float4 rv = *(const float4*)xr;
    const float4 ov = make_float4(acc[nt][0]+rv.x, acc[nt][1]+rv.y,
                                  acc[nt][2]+rv.z, acc[nt][3]+rv.w);
    *(float4*)(dst_f + ((size_t)bidx*NB_DM + n)*NB_E + e) = ov;
  }
}

// ---- fused attention: 1024 blocks, 16 q-rows per block, 4 waves x 256-col chunks ----
// XCD-aware decode: block n -> xcd = n&7 handles heads {2*(n&7), 2*(n&7)+1} only.
__global__ __launch_bounds__(256, 4) void k_attn(
    const unsigned short* __restrict__ Q, const unsigned short* __restrict__ K,
    const unsigned short* __restrict__ VT, const float* __restrict__ qr,
    const unsigned char* __restrict__ d8, float* __restrict__ attn_out,
    unsigned short* __restrict__ outb, float* __restrict__ ape_acc)
{
  __shared__ __align__(16) unsigned char smem[2048 + 32768];
  unsigned short* plds = (unsigned short*)(smem + 2048);
  float* qr_l = (float*)smem;                  // 96 f = 384B
  float* redm = (float*)(smem + 512);          // 64 f
  float* reds = (float*)(smem + 1024);         // 64 f

  const int tid = threadIdx.x;
  const int l = tid & 63, w = tid >> 6;
  const int lg = l >> 4, ll = l & 15;
  const int n = blockIdx.x;
  const int m = n >> 3;
  const int bh = (n & 7)*2 + (m >> 6);         // b*H + h
  const int b = bh >> 3;
  const int ib = (m & 63) << 4;

  for (int t = tid; t < 16*6; t += 256)
    qr_l[t] = qr[((size_t)bh*NB_E + ib + (t/6))*8 + (t % 6)];

  const unsigned short* Qb = Q + ((size_t)bh*NB_E + ib)*64;
  bf16x8 qf[2];
  #pragma unroll
  for (int hf = 0; hf < 2; ++hf)
    qf[hf] = *(const bf16x8*)(Qb + (size_t)ll*64 + hf*32 + lg*8);
  __syncthreads();

  // S = (Q/8) K^T ; wave w covers j in [w*256, w*256+256)
  f32x4 s[16];
  const unsigned short* Kb = K + (size_t)bh*NB_E*64;
  #pragma unroll
  for (int jt = 0; jt < 16; ++jt){
    const int jrow = (w*16 + jt)*16 + ll;
    bf16x8 k0 = *(const bf16x8*)(Kb + (size_t)jrow*64 + lg*8);
    bf16x8 k1 = *(const bf16x8*)(Kb + (size_t)jrow*64 + 32 + lg*8);
    f32x4 acc = {0.f,0.f,0.f,0.f};
    acc = mfma16(qf[0], k0, acc);
    acc = mfma16(qf[1], k1, acc);
    s[jt] = acc;
  }

  // + rpr bias, mask
  const unsigned char* d8r = d8 + ((size_t)b*NB_E + ib)*NB_E;
  #pragma unroll
  for (int jt = 0; jt < 16; ++jt){
    const int j = (w*16 + jt)*16 + ll;
    #pragma unroll
    for (int r = 0; r < 4; ++r){
      const int il = lg*4 + r;
      const unsigned char c = d8r[(size_t)il*NB_E + j];
      s[jt][r] = (c < 6) ? (s[jt][r] + qr_l[il*6 + c]) : NEGV;
    }
  }

  // row max across waves
  #pragma unroll
  for (int r = 0; r < 4; ++r){
    float mm = -3.0e38f;
    #pragma unroll
    for (int jt = 0; jt < 16; ++jt) mm = fmaxf(mm, s[jt][r]);
    mm = fmaxf(mm, __shfl_xor(mm, 1));
    mm = fmaxf(mm, __shfl_xor(mm, 2));
    mm = fmaxf(mm, __shfl_xor(mm, 4));
    mm = fmaxf(mm, __shfl_xor(mm, 8));
    if (ll == 0) redm[w*16 + lg*4 + r] = mm;
  }
  __syncthreads();
  float mx[4];
  #pragma unroll
  for (int r = 0; r < 4; ++r){
    const int il = lg*4 + r;
    mx[r] = fmaxf(fmaxf(redm[il], redm[16+il]), fmaxf(redm[32+il], redm[48+il]));
  }

  // exp + row sum across waves
  #pragma unroll
  for (int r = 0; r < 4; ++r){
    float sum = 0.f;
    #pragma unroll
    for (int jt = 0; jt < 16; ++jt){
      const float p = fast_exp2((s[jt][r] - mx[r]) * 1.4426950408889634f);
      s[jt][r] = p;
      sum += p;
    }
    sum += __shfl_xor(sum, 1);
    sum += __shfl_xor(sum, 2);
    sum += __shfl_xor(sum, 4);
    sum += __shfl_xor(sum, 8);
    if (ll == 0) reds[w*16 + lg*4 + r] = sum;
  }
  __syncthreads();
  float rinv[4];
  #pragma unroll
  for (int r = 0; r < 4; ++r){
    const int il = lg*4 + r;
    rinv[r] = 1.0f / (reds[il] + reds[16+il] + reds[32+il] + reds[48+il]);
  }

  // normalize: write attn (f32, nontemporal), P (bf16 LDS, XOR-swizzled), column sums
  float* arow = attn_out + ((size_t)bh*NB_E + ib)*NB_E;
  #pragma unroll
  for (int jt = 0; jt < 16; ++jt){
    const int j = (w*16 + jt)*16 + ll;
    float csum = 0.f;
    #pragma unroll
    for (int r = 0; r < 4; ++r){
      const int il = lg*4 + r;
      const float pn = s[jt][r] * rinv[r];
      __builtin_nontemporal_store(pn, &arow[(size_t)il*NB_E + j]);
      const int byo = ((il*1024 + j)*2) ^ ((il & 7) << 4);
      plds[byo >> 1] = f2bf(pn);
      csum += pn;
    }
    csum += __shfl_xor(csum, 16);
    csum += __shfl_xor(csum, 32);
    if (l < 16) atomicAdd(&ape_acc[(bh << 10) + j], csum);
  }
  __syncthreads();

  // PV: wave w -> dv chunk [w*16, w*16+16)
  const unsigned short* Vb = VT + ((size_t)bh*64 + w*16 + ll)*NB_E;
  f32x4 o = {0.f,0.f,0.f,0.f};
  #pragma unroll
  for (int kk = 0; kk < 32; ++kk){
    bf16x8 vf = *(const bf16x8*)(Vb + kk*32 + lg*8);
    const int byo = ((ll*2048 + (kk*32 + lg*8)*2)) ^ ((ll & 7) << 4);
    bf16x8 p = *(const bf16x8*)(smem + 2048 + byo);
    o = mfma16(p, vf, o);
  }
  const int coln = (bh & 7)*64 + w*16 + ll;
  #pragma unroll
  for (int r = 0; r < 4; ++r){
    const int e0 = ib + lg*4 + r;
    outb[((size_t)b*NB_E + e0)*512 + coln] = f2bf(o[r]);
  }
}

// ---- attn_per_edge finalize: sum per-head accumulators, divide by count ----
__global__ void k_ape(const float* __restrict__ acc, const int* __restrict__ cnt,
                      float* __restrict__ out){
  const int t = blockIdx.x*256 + threadIdx.x;
  if (t < NB_B*NB_E){
    const int b = t >> 10, j = t & 1023;
    float ssum = 0.f;
    #pragma unroll
    for (int h = 0; h < 8; ++h) ssum += acc[(((b<<3) + h) << 10) + j];
    const int c = cnt[t];
    out[t] = c > 0 ? ssum / (float)c : 0.f;
  }
}

extern "C" void kernel_launch(void* const* d_in, const int* in_sizes, int n_in,
                              void* d_out, int out_size, void* d_ws, size_t ws_size,
                              hipStream_t stream)
{
  const float* x        = (const float*)d_in[0];
  const int*   dist     = (const int*)d_in[1];
  const float* base_rpr = (const float*)d_in[2];
  const float* w_q      = (const float*)d_in[3];
  const float* w_k      = (const float*)d_in[4];
  const float* w_v      = (const float*)d_in[5];
  const float* w_fc     = (const float*)d_in[6];
  const float* ln_g     = (const float*)d_in[7];
  const float* ln_b     = (const float*)d_in[8];

  float* x_out    = (float*)d_out;
  float* attn_out = x_out + (size_t)NB_B*NB_DM*NB_E;
  float* ape_out  = attn_out + (size_t)NB_B*NB_H*NB_E*NB_E;

  unsigned char* ws = (unsigned char*)d_ws;
  unsigned short* s_bf   = (unsigned short*)(ws);
  unsigned short* qn_bf  = (unsigned short*)(ws + 2097152);
  unsigned short* wT     = (unsigned short*)(ws + 4194304);   // 4 x 512x512 bf16
  unsigned short* Qb     = (unsigned short*)(ws + 6291456);
  unsigned short* Kb     = (unsigned short*)(ws + 8388608);
  unsigned short* VTb    = (unsigned short*)(ws + 10485760);
  unsigned short* outb   = (unsigned short*)(ws + 12582912);
  float*          qr     = (float*)(ws + 14680064);           // 16*1024*8 f32 = 512KB
  unsigned char*  d8     = ws + 15204352;                     // 2MB
  int*            cnt    = (int*)(ws + 17301504);             // 8KB
  float*          apeacc = (float*)(ws + 17309696);           // 16*1024 f32 = 64KB

  hipMemsetAsync(cnt, 0, 8192 + 65536, stream);

  k_transpose_w<<<dim3(16,16,4), dim3(32,8), 0, stream>>>(w_q, w_k, w_v, w_fc, wT);
  k_transpose_x<<<dim3(32,16,2), dim3(32,8), 0, stream>>>(x, s_bf);
  k_ln<<<dim3(512), dim3(256), 0, stream>>>(s_bf, qn_bf, ln_g, ln_b);
  k_dist<<<dim3(64,2), dim3(256), 0, stream>>>(dist, d8, cnt);

  k_gemm_qkv<<<dim3(32,8,3), dim3(256), 0, stream>>>(qn_bf, s_bf, wT, base_rpr,
                                                     Qb, Kb, VTb, qr);

  k_attn<<<dim3(1024), dim3(256), 0, stream>>>(Qb, Kb, VTb, qr, d8, attn_out, outb, apeacc);

  k_fc<<<dim3(32,8), dim3(256), 0, stream>>>(outb, wT + 786432, x_out, x);
  k_ape<<<dim3(8), dim3(256), 0, stream>>>(apeacc, cnt, ape_out);
}